// Round 9
// baseline (247.512 us; speedup 1.0000x reference)
//
#include <hip/hip_runtime.h>
#include <cfloat>
#include <stdint.h>

// z: [32768, 32] fp32 rows; emb: [8192, 32] fp32 codes.
// Outputs (fp32, concat): quantized[1048576] | vq_loss | commit_loss | idx[32768]
//
// R9: fused bf16-MFMA filter + exact fp32 re-check.
//  - grid 512 x 256thr (4 waves); block = 64 rows x all 8192 codes;
//    LDS ~41KB + launch_bounds(256,2) -> 2 blocks/CU (R8: 130KB -> 1 wave/SIMD,
//    all latency exposed)
//  - emit path: packed 4-bit mask + __ffs drain, ONE branch per tile
//    (R8: 8 serialized exec-masked atomic blocks, taken most tiles = 456k cyc)
//  - eh pre-permuted to MFMA fragment order in prep -> staging is linear
//    copies; hot ds_read_b128 on consecutive lanes = conflict-free
//  - threshold th = rowmax - EPS, butterfly-shared every 256-code chunk
#define NROW   32768
#define KCODES 8192
#define CDIM   32
#define OUT_Q    0
#define OUT_LOSS 1048576
#define OUT_IDX  1048578
#define EPS      6e-5f    // >= 2.5x worst-row bf16+grid error bound (~2.4e-5)
#define MAXCAND  32
#define RB       64                  // rows per block (16 per wave)
#define CHUNK    256                 // codes per staged chunk (16 KB)
#define NIT      (KCODES / CHUNK)    // 32
#define TPC      (CHUNK / 16)        // 16 tiles per chunk

typedef short bf8_t __attribute__((ext_vector_type(8)));   // 8 bf16
typedef float f32x4 __attribute__((ext_vector_type(4)));

__device__ __forceinline__ unsigned short f2bf(float f) {  // RNE float->bf16
  unsigned int u = __float_as_uint(f);
  return (unsigned short)((u + 0x7FFFu + ((u >> 16) & 1u)) >> 16);
}

// ---------------------------------------------------------------------------
// Prep: enorm[k] = ||emb_k||^2 (bit-identical R2..R8 chain); eh_perm = bf16
// codebook in MFMA B-fragment order: f4 slot [t*64 + q*16 + col] holds
// bf16 e[t*16+col][q*8 .. q*8+7]. Zero loss slots. grid = 32 x 256.
// ---------------------------------------------------------------------------
__global__ __launch_bounds__(256) void vq_prep(
    const float* __restrict__ emb, uint4* __restrict__ ep,
    float* __restrict__ enorm, float* __restrict__ out) {
  const int k = blockIdx.x * 256 + threadIdx.x;  // code id
  const float4* e4 = (const float4*)(emb + (size_t)k * CDIM);
  float s = 0.f;
  unsigned int w[16];
#pragma unroll
  for (int j = 0; j < 8; ++j) {
    float4 v = e4[j];
    s += v.x * v.x + v.y * v.y + v.z * v.z + v.w * v.w;
    w[2 * j]     = (unsigned int)f2bf(v.x) | ((unsigned int)f2bf(v.y) << 16);
    w[2 * j + 1] = (unsigned int)f2bf(v.z) | ((unsigned int)f2bf(v.w) << 16);
  }
  enorm[k] = s;
  const int t = k >> 4, col = k & 15;
#pragma unroll
  for (int q = 0; q < 4; ++q)
    ep[t * 64 + q * 16 + col] =
        make_uint4(w[4 * q], w[4 * q + 1], w[4 * q + 2], w[4 * q + 3]);
  if (blockIdx.x == 0 && threadIdx.x < 2) out[OUT_LOSS + threadIdx.x] = 0.f;
}

// ---------------------------------------------------------------------------
// Fused sweep + exact finalize. grid = NROW/RB = 512 blocks x 256 threads.
// Wave wid owns rows rbase + wid*16 .. +16 (1 A-frag, 1 MFMA per tile).
// ---------------------------------------------------------------------------
__global__ __launch_bounds__(256, 2) void vq_sweep(
    const float* __restrict__ z, const float* __restrict__ emb,
    const float4* __restrict__ ep4, const float* __restrict__ enorm,
    float* __restrict__ out) {
  __shared__ float4 ebuf[2][CHUNK * 4];   // 32 KB, fragment-ordered
  __shared__ int s_cnt[RB];
  __shared__ int s_cand[RB * MAXCAND];    // 8 KB
  __shared__ int s_bidx[RB];
  __shared__ int s_ovf[RB];
  __shared__ int s_ovfn;
  __shared__ float s_loss[4];

  const int tid = threadIdx.x;
  const int wid = tid >> 6, lane = tid & 63;
  const int quad = lane >> 4, col = lane & 15;
  const int rbase = blockIdx.x * RB;

  if (tid < RB) s_cnt[tid] = 0;
  if (tid == 0) s_ovfn = 0;

  // A-fragment: A[m=col][k=quad*8+j] = bf16(z[rbase + wid*16 + col][...])
  bf8_t a;
  {
    const float4* zz = (const float4*)(
        z + (size_t)(rbase + wid * 16 + col) * CDIM + quad * 8);
    float4 v0 = zz[0], v1 = zz[1];
    a[0] = (short)f2bf(v0.x); a[1] = (short)f2bf(v0.y);
    a[2] = (short)f2bf(v0.z); a[3] = (short)f2bf(v0.w);
    a[4] = (short)f2bf(v1.x); a[5] = (short)f2bf(v1.y);
    a[6] = (short)f2bf(v1.z); a[7] = (short)f2bf(v1.w);
  }

  // stage chunk 0 (linear: ep4 is already fragment-ordered)
#pragma unroll
  for (int s = 0; s < 4; ++s) ebuf[0][tid + s * 256] = ep4[tid + s * 256];
  __syncthreads();

  float rm[4] = {-FLT_MAX, -FLT_MAX, -FLT_MAX, -FLT_MAX};

  // Warm-up: chunk 0 max-only (prevents cold-start emit flood).
#pragma unroll 4
  for (int t = 0; t < TPC; ++t) {
    bf8_t b = *(const bf8_t*)&ebuf[0][t * 64 + lane];
    f32x4 d = __builtin_amdgcn_mfma_f32_16x16x32_bf16(
        a, b, (f32x4){0.f, 0.f, 0.f, 0.f}, 0, 0, 0);
#pragma unroll
    for (int i = 0; i < 4; ++i) rm[i] = fmaxf(rm[i], d[i]);
  }
  float th[4];
#pragma unroll
  for (int off = 1; off < 16; off <<= 1)
#pragma unroll
    for (int i = 0; i < 4; ++i) rm[i] = fmaxf(rm[i], __shfl_xor(rm[i], off, 64));
#pragma unroll
  for (int i = 0; i < 4; ++i) th[i] = rm[i] - EPS;

  float4 st[4];
  for (int ic = 0; ic < NIT; ++ic) {
    const int p = ic & 1;
    if (ic + 1 < NIT) {  // prefetch next chunk (linear, hidden under compute)
      const int gb = (ic + 1) * CHUNK * 4;
#pragma unroll
      for (int s = 0; s < 4; ++s) st[s] = ep4[gb + tid + s * 256];
    }

    const int cbase = ic * CHUNK;
#pragma unroll 4
    for (int t = 0; t < TPC; ++t) {
      bf8_t b = *(const bf8_t*)&ebuf[p][t * 64 + lane];
      f32x4 d = __builtin_amdgcn_mfma_f32_16x16x32_bf16(
          a, b, (f32x4){0.f, 0.f, 0.f, 0.f}, 0, 0, 0);
      unsigned m = 0;
      m |= d[0] >= th[0] ? 1u : 0u;
      m |= d[1] >= th[1] ? 2u : 0u;
      m |= d[2] >= th[2] ? 4u : 0u;
      m |= d[3] >= th[3] ? 8u : 0u;
      if (m) {  // one branch; drain set bits (typically 1)
        const int code = cbase + t * 16 + col;
        const int rl = wid * 16 + quad * 4;
        do {
          int i = __ffs(m) - 1;
          m &= m - 1;
          int s2 = atomicAdd(&s_cnt[rl + i], 1);
          if (s2 < MAXCAND) s_cand[(rl + i) * MAXCAND + s2] = code;
        } while (m);
      }
#pragma unroll
      for (int i = 0; i < 4; ++i) rm[i] = fmaxf(rm[i], d[i]);
    }

    if (ic + 1 < NIT) {  // linear LDS writes: conflict-free
#pragma unroll
      for (int s = 0; s < 4; ++s) ebuf[p ^ 1][tid + s * 256] = st[s];
    }
    __syncthreads();

    // share per-row running max across the row's 16 lanes; refresh threshold
#pragma unroll
    for (int off = 1; off < 16; off <<= 1)
#pragma unroll
      for (int i = 0; i < 4; ++i)
        rm[i] = fmaxf(rm[i], __shfl_xor(rm[i], off, 64));
#pragma unroll
    for (int i = 0; i < 4; ++i) th[i] = rm[i] - EPS;
  }

  // ---- exact finalize phase 1: one thread per row (candidate path) ----
  if (tid < RB) {
    const int r = rbase + tid;
    const int n = s_cnt[tid];
    if (n <= MAXCAND) {
      float zr[CDIM];
      const float4* z4 = (const float4*)(z + (size_t)r * CDIM);
#pragma unroll
      for (int j = 0; j < 8; ++j) {
        float4 v = z4[j];
        zr[4 * j + 0] = v.x; zr[4 * j + 1] = v.y;
        zr[4 * j + 2] = v.z; zr[4 * j + 3] = v.w;
      }
      float znorm = 0.f;
#pragma unroll
      for (int j = 0; j < CDIM; ++j) znorm = fmaf(zr[j], zr[j], znorm);

      float best = FLT_MAX;
      int bidx = KCODES;
      for (int j = 0; j < n; ++j) {
        int k = s_cand[tid * MAXCAND + j];
        const float4* ek4 = (const float4*)(emb + (size_t)k * CDIM);
        float dot = 0.f;
#pragma unroll
        for (int q = 0; q < 8; ++q) {  // ascending j: reference fmaf order
          float4 e = ek4[q];
          dot = fmaf(zr[4 * q + 0], e.x, dot);
          dot = fmaf(zr[4 * q + 1], e.y, dot);
          dot = fmaf(zr[4 * q + 2], e.z, dot);
          dot = fmaf(zr[4 * q + 3], e.w, dot);
        }
        float s = fmaf(-2.f, dot, znorm) + enorm[k];
        if (s < best || (s == best && k < bidx)) { best = s; bidx = k; }
      }
      s_bidx[tid] = bidx;
    } else {
      int o = atomicAdd(&s_ovfn, 1);  // overflow: defer to cooperative scan
      s_ovf[o] = tid;
    }
  }
  __syncthreads();

  // ---- phase 2 (insurance, P~0): wave-cooperative exact full scan ----
  const int novf = s_ovfn;
  for (int e = wid; e < novf; e += 4) {
    const int rl = s_ovf[e];
    const int r = rbase + rl;
    float zr[CDIM];
    const float4* z4 = (const float4*)(z + (size_t)r * CDIM);
#pragma unroll
    for (int j = 0; j < 8; ++j) {
      float4 v = z4[j];
      zr[4 * j + 0] = v.x; zr[4 * j + 1] = v.y;
      zr[4 * j + 2] = v.z; zr[4 * j + 3] = v.w;
    }
    float znorm = 0.f;
#pragma unroll
    for (int j = 0; j < CDIM; ++j) znorm = fmaf(zr[j], zr[j], znorm);

    float best = FLT_MAX;
    int bidx = KCODES;
    const int k0 = lane * (KCODES / 64);
    for (int k = k0; k < k0 + KCODES / 64; ++k) {  // 128 codes per lane
      const float4* ek4 = (const float4*)(emb + (size_t)k * CDIM);
      float dot = 0.f;
#pragma unroll
      for (int q = 0; q < 8; ++q) {
        float4 ev = ek4[q];
        dot = fmaf(zr[4 * q + 0], ev.x, dot);
        dot = fmaf(zr[4 * q + 1], ev.y, dot);
        dot = fmaf(zr[4 * q + 2], ev.z, dot);
        dot = fmaf(zr[4 * q + 3], ev.w, dot);
      }
      float s = fmaf(-2.f, dot, znorm) + enorm[k];
      if (s < best) { best = s; bidx = k; }
    }
    // lexicographic (s, k) min == first-index argmin; s>0 -> bits monotone
    unsigned long long key =
        ((unsigned long long)__float_as_uint(best) << 13) |
        (unsigned long long)bidx;
#pragma unroll
    for (int off = 1; off < 64; off <<= 1) {
      unsigned long long o2 = __shfl_xor(key, off, 64);
      key = o2 < key ? o2 : key;
    }
    if (lane == 0) s_bidx[rl] = (int)(key & (unsigned long long)(KCODES - 1));
  }
  __syncthreads();

  // ---- gather + idx + losses: 256 threads over RB*8 = 512 float4s ----
  float lsum = 0.f;
  const float4* emb4 = (const float4*)emb;
  const float4* z4g = (const float4*)z;
  float4* o4 = (float4*)(out + OUT_Q);
#pragma unroll
  for (int i2 = 0; i2 < (RB * 8) / 256; ++i2) {  // 2 iters
    const int i = i2 * 256 + tid;
    const int row = i >> 3, j = i & 7;
    const int b = s_bidx[row];
    float4 q = emb4[(size_t)b * 8 + j];
    float4 zz = z4g[((size_t)rbase + row) * 8 + j];
    float dx = zz.x - q.x, dy = zz.y - q.y, dz = zz.z - q.z, dw = zz.w - q.w;
    lsum += dx * dx + dy * dy + dz * dz + dw * dw;
    o4[((size_t)rbase + row) * 8 + j] = q;
    if (j == 0) out[OUT_IDX + rbase + row] = (float)b;
  }
#pragma unroll
  for (int off = 32; off > 0; off >>= 1) lsum += __shfl_down(lsum, off, 64);
  if (lane == 0) s_loss[wid] = lsum;
  __syncthreads();
  if (tid == 0) {
    float v = (s_loss[0] + s_loss[1] + s_loss[2] + s_loss[3]) *
              (1.0f / (float)(NROW * CDIM));
    atomicAdd(out + OUT_LOSS + 0, v);
    atomicAdd(out + OUT_LOSS + 1, v);
  }
}

// ---------------------------------------------------------------------------
extern "C" void kernel_launch(void* const* d_in, const int* in_sizes, int n_in,
                              void* d_out, int out_size, void* d_ws,
                              size_t ws_size, hipStream_t stream) {
  const float* z = (const float*)d_in[0];
  const float* emb = (const float*)d_in[1];
  float* out = (float*)d_out;

  // ws: enorm 32KB | eh_perm 512KB
  float* enorm = (float*)d_ws;
  uint4* ep = (uint4*)(enorm + KCODES);

  vq_prep<<<KCODES / 256, 256, 0, stream>>>(emb, ep, enorm, out);
  vq_sweep<<<NROW / RB, 256, 0, stream>>>(z, emb, (const float4*)ep, enorm,
                                          out);
}

// Round 10
// 216.258 us; speedup vs baseline: 1.1445x; 1.1445x over previous
//
#include <hip/hip_runtime.h>
#include <cfloat>
#include <stdint.h>

// z: [32768, 32] fp32 rows; emb: [8192, 32] fp32 codes.
// Outputs (fp32, concat): quantized[1048576] | vq_loss | commit_loss | idx[32768]
//
// R10: fused bf16-MFMA filter + exact fp32 re-check.
//  - hot tile loop is BRANCHLESS: compares packed into a 64-bit per-lane mask
//    (16 tiles x 4 rows = 64 bits); ONE drain branch per 256-code chunk.
//    (R7-R9 plateaued at ~190us because the emit branch + LDS atomics inside
//    the tile loop blocked ds_read/MFMA software pipelining: 468k cyc/block
//    vs 40k floor, VALUBusy 18%, MfmaUtil 3.5%.)
//  - eh pre-permuted to MFMA B-fragment order (linear staging, conflict-free)
//  - LDS ~42KB + launch_bounds(256,2): 2 blocks/CU
//  - threshold th = rowmax - EPS, butterfly-shared per chunk (stale = superset)
#define NROW   32768
#define KCODES 8192
#define CDIM   32
#define OUT_Q    0
#define OUT_LOSS 1048576
#define OUT_IDX  1048578
#define EPS      6e-5f    // >= 2.5x worst-row bf16+grid error bound (~2.4e-5)
#define MAXCAND  32
#define RB       64                  // rows per block (16 per wave)
#define CHUNK    256                 // codes per staged chunk (16 KB)
#define NIT      (KCODES / CHUNK)    // 32
#define TPC      (CHUNK / 16)        // 16 tiles per chunk == 64 mask bits

typedef short bf8_t __attribute__((ext_vector_type(8)));   // 8 bf16
typedef float f32x4 __attribute__((ext_vector_type(4)));

__device__ __forceinline__ unsigned short f2bf(float f) {  // RNE float->bf16
  unsigned int u = __float_as_uint(f);
  return (unsigned short)((u + 0x7FFFu + ((u >> 16) & 1u)) >> 16);
}

// ---------------------------------------------------------------------------
// Prep: enorm[k] = ||emb_k||^2 (bit-identical R2..R9 chain); ep = bf16
// codebook in MFMA B-fragment order: f4 slot [t*64 + q*16 + col] holds
// bf16 e[t*16+col][q*8 .. q*8+7]. Zero loss slots. grid = 32 x 256.
// ---------------------------------------------------------------------------
__global__ __launch_bounds__(256) void vq_prep(
    const float* __restrict__ emb, uint4* __restrict__ ep,
    float* __restrict__ enorm, float* __restrict__ out) {
  const int k = blockIdx.x * 256 + threadIdx.x;  // code id
  const float4* e4 = (const float4*)(emb + (size_t)k * CDIM);
  float s = 0.f;
  unsigned int w[16];
#pragma unroll
  for (int j = 0; j < 8; ++j) {
    float4 v = e4[j];
    s += v.x * v.x + v.y * v.y + v.z * v.z + v.w * v.w;
    w[2 * j]     = (unsigned int)f2bf(v.x) | ((unsigned int)f2bf(v.y) << 16);
    w[2 * j + 1] = (unsigned int)f2bf(v.z) | ((unsigned int)f2bf(v.w) << 16);
  }
  enorm[k] = s;
  const int t = k >> 4, col = k & 15;
#pragma unroll
  for (int q = 0; q < 4; ++q)
    ep[t * 64 + q * 16 + col] =
        make_uint4(w[4 * q], w[4 * q + 1], w[4 * q + 2], w[4 * q + 3]);
  if (blockIdx.x == 0 && threadIdx.x < 2) out[OUT_LOSS + threadIdx.x] = 0.f;
}

// ---------------------------------------------------------------------------
// Fused sweep + exact finalize. grid = NROW/RB = 512 blocks x 256 threads.
// Wave wid owns rows rbase + wid*16 .. +16 (1 A-frag, 1 MFMA per tile).
// ---------------------------------------------------------------------------
__global__ __launch_bounds__(256, 2) void vq_sweep(
    const float* __restrict__ z, const float* __restrict__ emb,
    const float4* __restrict__ ep4, const float* __restrict__ enorm,
    float* __restrict__ out) {
  __shared__ float4 ebuf[2][CHUNK * 4];   // 32 KB, fragment-ordered
  __shared__ int s_cnt[RB];
  __shared__ int s_cand[RB * MAXCAND];    // 8 KB
  __shared__ int s_bidx[RB];
  __shared__ int s_ovf[RB];
  __shared__ int s_ovfn;
  __shared__ float s_loss[4];

  const int tid = threadIdx.x;
  const int wid = tid >> 6, lane = tid & 63;
  const int quad = lane >> 4, col = lane & 15;
  const int rbase = blockIdx.x * RB;

  if (tid < RB) s_cnt[tid] = 0;
  if (tid == 0) s_ovfn = 0;

  // A-fragment: A[m=col][k=quad*8+j] = bf16(z[rbase + wid*16 + col][...])
  bf8_t a;
  {
    const float4* zz = (const float4*)(
        z + (size_t)(rbase + wid * 16 + col) * CDIM + quad * 8);
    float4 v0 = zz[0], v1 = zz[1];
    a[0] = (short)f2bf(v0.x); a[1] = (short)f2bf(v0.y);
    a[2] = (short)f2bf(v0.z); a[3] = (short)f2bf(v0.w);
    a[4] = (short)f2bf(v1.x); a[5] = (short)f2bf(v1.y);
    a[6] = (short)f2bf(v1.z); a[7] = (short)f2bf(v1.w);
  }

  // stage chunk 0 (linear: ep4 is already fragment-ordered)
#pragma unroll
  for (int s = 0; s < 4; ++s) ebuf[0][tid + s * 256] = ep4[tid + s * 256];
  __syncthreads();

  float rm[4] = {-FLT_MAX, -FLT_MAX, -FLT_MAX, -FLT_MAX};

  // Warm-up: chunk 0 max-only, branchless (prevents cold-start emit flood).
#pragma unroll
  for (int t = 0; t < TPC; ++t) {
    bf8_t b = *(const bf8_t*)&ebuf[0][t * 64 + lane];
    f32x4 d = __builtin_amdgcn_mfma_f32_16x16x32_bf16(
        a, b, (f32x4){0.f, 0.f, 0.f, 0.f}, 0, 0, 0);
#pragma unroll
    for (int i = 0; i < 4; ++i) rm[i] = fmaxf(rm[i], d[i]);
  }
  float th[4];
#pragma unroll
  for (int off = 1; off < 16; off <<= 1)
#pragma unroll
    for (int i = 0; i < 4; ++i) rm[i] = fmaxf(rm[i], __shfl_xor(rm[i], off, 64));
#pragma unroll
  for (int i = 0; i < 4; ++i) th[i] = rm[i] - EPS;

  float4 st[4];
  for (int ic = 0; ic < NIT; ++ic) {
    const int p = ic & 1;
    if (ic + 1 < NIT) {  // prefetch next chunk (linear, hidden under compute)
      const int gb = (ic + 1) * CHUNK * 4;
#pragma unroll
      for (int s = 0; s < 4; ++s) st[s] = ep4[gb + tid + s * 256];
    }

    // ---- hot tile loop: NO branches, NO LDS atomics -> pipelineable ----
    unsigned long long msk = 0ull;
#pragma unroll
    for (int t = 0; t < TPC; ++t) {
      bf8_t b = *(const bf8_t*)&ebuf[p][t * 64 + lane];
      f32x4 d = __builtin_amdgcn_mfma_f32_16x16x32_bf16(
          a, b, (f32x4){0.f, 0.f, 0.f, 0.f}, 0, 0, 0);
      unsigned n = (unsigned)(d[0] >= th[0]) | ((unsigned)(d[1] >= th[1]) << 1) |
                   ((unsigned)(d[2] >= th[2]) << 2) |
                   ((unsigned)(d[3] >= th[3]) << 3);
      msk |= (unsigned long long)n << (4 * t);
#pragma unroll
      for (int i = 0; i < 4; ++i) rm[i] = fmaxf(rm[i], d[i]);
    }

    if (ic + 1 < NIT) {  // linear LDS writes: conflict-free
#pragma unroll
      for (int s = 0; s < 4; ++s) ebuf[p ^ 1][tid + s * 256] = st[s];
    }

    // ---- deferred drain: ONE branch per chunk (typically few lanes) ----
    if (msk) {
      const int cbase = ic * CHUNK;
      const int rl = wid * 16 + quad * 4;
      do {
        int bpos = __ffsll((unsigned long long)msk) - 1;
        msk &= msk - 1;
        int t = bpos >> 2, i = bpos & 3;
        int code = cbase + t * 16 + col;
        int s2 = atomicAdd(&s_cnt[rl + i], 1);
        if (s2 < MAXCAND) s_cand[(rl + i) * MAXCAND + s2] = code;
      } while (msk);
    }
    __syncthreads();

    // share per-row running max across the row's 16 lanes; refresh threshold
#pragma unroll
    for (int off = 1; off < 16; off <<= 1)
#pragma unroll
      for (int i = 0; i < 4; ++i)
        rm[i] = fmaxf(rm[i], __shfl_xor(rm[i], off, 64));
#pragma unroll
    for (int i = 0; i < 4; ++i) th[i] = rm[i] - EPS;
  }

  // ---- exact finalize phase 1: one thread per row (candidate path) ----
  if (tid < RB) {
    const int r = rbase + tid;
    const int n = s_cnt[tid];
    if (n <= MAXCAND) {
      float zr[CDIM];
      const float4* z4 = (const float4*)(z + (size_t)r * CDIM);
#pragma unroll
      for (int j = 0; j < 8; ++j) {
        float4 v = z4[j];
        zr[4 * j + 0] = v.x; zr[4 * j + 1] = v.y;
        zr[4 * j + 2] = v.z; zr[4 * j + 3] = v.w;
      }
      float znorm = 0.f;
#pragma unroll
      for (int j = 0; j < CDIM; ++j) znorm = fmaf(zr[j], zr[j], znorm);

      float best = FLT_MAX;
      int bidx = KCODES;
      for (int j = 0; j < n; ++j) {
        int k = s_cand[tid * MAXCAND + j];
        const float4* ek4 = (const float4*)(emb + (size_t)k * CDIM);
        float dot = 0.f;
#pragma unroll
        for (int q = 0; q < 8; ++q) {  // ascending j: reference fmaf order
          float4 e = ek4[q];
          dot = fmaf(zr[4 * q + 0], e.x, dot);
          dot = fmaf(zr[4 * q + 1], e.y, dot);
          dot = fmaf(zr[4 * q + 2], e.z, dot);
          dot = fmaf(zr[4 * q + 3], e.w, dot);
        }
        float s = fmaf(-2.f, dot, znorm) + enorm[k];
        if (s < best || (s == best && k < bidx)) { best = s; bidx = k; }
      }
      s_bidx[tid] = bidx;
    } else {
      int o = atomicAdd(&s_ovfn, 1);  // overflow: defer to cooperative scan
      s_ovf[o] = tid;
    }
  }
  __syncthreads();

  // ---- phase 2 (insurance, P~0): wave-cooperative exact full scan ----
  const int novf = s_ovfn;
  for (int e = wid; e < novf; e += 4) {
    const int rl = s_ovf[e];
    const int r = rbase + rl;
    float zr[CDIM];
    const float4* z4 = (const float4*)(z + (size_t)r * CDIM);
#pragma unroll
    for (int j = 0; j < 8; ++j) {
      float4 v = z4[j];
      zr[4 * j + 0] = v.x; zr[4 * j + 1] = v.y;
      zr[4 * j + 2] = v.z; zr[4 * j + 3] = v.w;
    }
    float znorm = 0.f;
#pragma unroll
    for (int j = 0; j < CDIM; ++j) znorm = fmaf(zr[j], zr[j], znorm);

    float best = FLT_MAX;
    int bidx = KCODES;
    const int k0 = lane * (KCODES / 64);
    for (int k = k0; k < k0 + KCODES / 64; ++k) {  // 128 codes per lane
      const float4* ek4 = (const float4*)(emb + (size_t)k * CDIM);
      float dot = 0.f;
#pragma unroll
      for (int q = 0; q < 8; ++q) {
        float4 ev = ek4[q];
        dot = fmaf(zr[4 * q + 0], ev.x, dot);
        dot = fmaf(zr[4 * q + 1], ev.y, dot);
        dot = fmaf(zr[4 * q + 2], ev.z, dot);
        dot = fmaf(zr[4 * q + 3], ev.w, dot);
      }
      float s = fmaf(-2.f, dot, znorm) + enorm[k];
      if (s < best) { best = s; bidx = k; }
    }
    // lexicographic (s, k) min == first-index argmin; s>0 -> bits monotone
    unsigned long long key =
        ((unsigned long long)__float_as_uint(best) << 13) |
        (unsigned long long)bidx;
#pragma unroll
    for (int off = 1; off < 64; off <<= 1) {
      unsigned long long o2 = __shfl_xor(key, off, 64);
      key = o2 < key ? o2 : key;
    }
    if (lane == 0) s_bidx[rl] = (int)(key & (unsigned long long)(KCODES - 1));
  }
  __syncthreads();

  // ---- gather + idx + losses: 256 threads over RB*8 = 512 float4s ----
  float lsum = 0.f;
  const float4* emb4 = (const float4*)emb;
  const float4* z4g = (const float4*)z;
  float4* o4 = (float4*)(out + OUT_Q);
#pragma unroll
  for (int i2 = 0; i2 < (RB * 8) / 256; ++i2) {  // 2 iters
    const int i = i2 * 256 + tid;
    const int row = i >> 3, j = i & 7;
    const int b = s_bidx[row];
    float4 q = emb4[(size_t)b * 8 + j];
    float4 zz = z4g[((size_t)rbase + row) * 8 + j];
    float dx = zz.x - q.x, dy = zz.y - q.y, dz = zz.z - q.z, dw = zz.w - q.w;
    lsum += dx * dx + dy * dy + dz * dz + dw * dw;
    o4[((size_t)rbase + row) * 8 + j] = q;
    if (j == 0) out[OUT_IDX + rbase + row] = (float)b;
  }
#pragma unroll
  for (int off = 32; off > 0; off >>= 1) lsum += __shfl_down(lsum, off, 64);
  if (lane == 0) s_loss[wid] = lsum;
  __syncthreads();
  if (tid == 0) {
    float v = (s_loss[0] + s_loss[1] + s_loss[2] + s_loss[3]) *
              (1.0f / (float)(NROW * CDIM));
    atomicAdd(out + OUT_LOSS + 0, v);
    atomicAdd(out + OUT_LOSS + 1, v);
  }
}

// ---------------------------------------------------------------------------
extern "C" void kernel_launch(void* const* d_in, const int* in_sizes, int n_in,
                              void* d_out, int out_size, void* d_ws,
                              size_t ws_size, hipStream_t stream) {
  const float* z = (const float*)d_in[0];
  const float* emb = (const float*)d_in[1];
  float* out = (float*)d_out;

  // ws: enorm 32KB | ep (fragment-ordered bf16 codebook) 512KB
  float* enorm = (float*)d_ws;
  uint4* ep = (uint4*)(enorm + KCODES);

  vq_prep<<<KCODES / 256, 256, 0, stream>>>(emb, ep, enorm, out);
  vq_sweep<<<NROW / RB, 256, 0, stream>>>(z, emb, (const float4*)ep, enorm,
                                          out);
}